// Round 13
// baseline (259.853 us; speedup 1.0000x reference)
//
#include <hip/hip_runtime.h>

typedef float  f32x4  __attribute__((ext_vector_type(4)));
typedef short  bf16x8 __attribute__((ext_vector_type(8)));

#define TWOLOG2E   2.8853900817779268f
#define NLOG2E    -1.4426950408889634f
#define NTWOLOG2E -2.8853900817779268f

__device__ __forceinline__ unsigned short f2b(float f) {      // fp32 -> bf16 RNE
    unsigned int u = __builtin_bit_cast(unsigned int, f);
    u += 0x7fffu + ((u >> 16) & 1u);
    return (unsigned short)(u >> 16);
}
__device__ __forceinline__ float b2f(unsigned short s) {
    unsigned int u = ((unsigned int)s) << 16;
    return __builtin_bit_cast(float, u);
}
__device__ __forceinline__ unsigned int pk2(float lo, float hi) {
#if __has_builtin(__builtin_amdgcn_cvt_pk_bf16_f32)
    typedef __bf16 bf16x2 __attribute__((ext_vector_type(2)));
    bf16x2 p = __builtin_amdgcn_cvt_pk_bf16_f32(lo, hi);
    return __builtin_bit_cast(unsigned int, p);
#else
    return (unsigned int)f2b(lo) | ((unsigned int)f2b(hi) << 16);
#endif
}
__device__ __forceinline__ float frcp(float x) { return __builtin_amdgcn_rcpf(x); }
__device__ __forceinline__ float fex2(float x) { return __builtin_amdgcn_exp2f(x); }

// FULLY DECOUPLED (R12 structure) + AGPR-resident weights.
// block = 1 wave = 64 thr; wave owns 16 rows through ALL 4 layers, t=0..63.
// grid 1024 = 4 blocks/CU = 1 wave/SIMD. The 64 weight B-frags (4l x 8g x 2c,
// 4 regs each = 256 regs) are FORCED into AGPRs via inline-asm MFMA with "a"
// operand constraints (gfx950 MFMA reads B from AGPR) -> arch-VGPR use ~130,
// no scratch spill (R12's failure). Two asm blocks per (t,l):
//   R: acc[g] = mfma(a1, Wrec[g], 0)   -- recurrent first, covers a0 ds_read
//   I: acc[g] = mfma(a0, Winp[g], acc[g]) + 2x s_nop 7
// MFMA->MFMA same-D chaining needs no waits; the trailing s_nops cover the
// un-scoreboarded MFMA->VALU-read hazard (asm bypasses the hazard recognizer).
// Bias added in the epilogue (4 v_add/cell). Epilogue: 5 exp + 2 rcp per cell
// (merged-rcp shared-denominator algebra), cell state pre-scaled (-2log2e*c).
__global__ __launch_bounds__(64, 1)
void lstm_mfma(const float* __restrict__ xg,  const float* __restrict__ Wih0,
               const float* __restrict__ Wih, const float* __restrict__ Whh,
               const float* __restrict__ bih, const float* __restrict__ bhh,
               const float* __restrict__ Wlin,const float* __restrict__ blin,
               float* __restrict__ out) {
    __shared__ short        hbuf[4 * 640] __attribute__((aligned(16))); // [l][16row*40]
    __shared__ unsigned int xb[64 * 16];                                // [t][row] 2xbf16

    const int lane = threadIdx.x;      // 0..63
    const int m    = lane & 15;        // A-row / D-col index
    const int q    = lane >> 4;        // quad
    const int row0 = blockIdx.x * 16;

    for (int i = lane; i < 1280; i += 64) ((unsigned int*)hbuf)[i] = 0u;

    for (int i = lane; i < 1024; i += 64) {
        int r = i >> 6, t = i & 63;
        float x0 = xg[(size_t)(row0 + r) * 192 + t];
        float x1 = xg[(size_t)(row0 + r) * 192 + 64 + t];
        xb[t * 16 + r] = pk2(x0, x1);
    }

    // ---- one-time gather: B-frags + bias for ALL 4 layers (negated scales) ----
    bf16x8 bfr[4][8][2];
    float  bv[4][8];
#pragma unroll
    for (int l = 0; l < 4; ++l) {
#pragma unroll
        for (int g = 0; g < 8; ++g) {
            const int   T    = g >> 1;
            const int   rowG = T * 32 + 2 * m + (g & 1);
            const float sc   = (T == 2) ? NTWOLOG2E : NLOG2E;
            bv[l][g] = (bih[l * 128 + rowG] + bhh[l * 128 + rowG]) * sc;
#pragma unroll
            for (int c = 0; c < 2; ++c) {
                const int k0 = c * 32 + q * 8;
                float w[8];
                if (l == 0) {
                    if (c == 0) {
#pragma unroll
                        for (int jj = 0; jj < 8; ++jj) w[jj] = 0.0f;
                        if (q == 0) { w[0] = Wih0[rowG * 2]; w[1] = Wih0[rowG * 2 + 1]; }
                    } else {
                        const float* src = Whh + rowG * 32 + (k0 - 32);
#pragma unroll
                        for (int jj = 0; jj < 8; ++jj) w[jj] = src[jj];
                    }
                } else {
                    const float* src = (c == 0) ? (Wih + (l - 1) * 4096 + rowG * 32 + k0)
                                                : (Whh + l * 4096 + rowG * 32 + (k0 - 32));
#pragma unroll
                    for (int jj = 0; jj < 8; ++jj) w[jj] = src[jj];
                }
                bf16x8 fr;
#pragma unroll
                for (int jj = 0; jj < 8; ++jj) fr[jj] = (short)f2b(w[jj] * sc);
                bfr[l][g][c] = fr;
            }
        }
    }

    float cp[4][2][4];   // scaled cell state -2log2e*c
#pragma unroll
    for (int l = 0; l < 4; ++l)
#pragma unroll
        for (int hf = 0; hf < 2; ++hf)
#pragma unroll
            for (int r = 0; r < 4; ++r) cp[l][hf][r] = 0.0f;

    f32x4 zz = {0.f, 0.f, 0.f, 0.f};   // MFMA C init, hoisted to 4 VGPRs once

    __syncthreads();

    const int aoff = m * 40 + q * 8;

    for (int t = 0; t < 64; ++t) {
#pragma unroll
        for (int l = 0; l < 4; ++l) {
            bf16x8 a1 = *(const bf16x8*)(hbuf + l * 640 + aoff);   // h_l(t-1)
            bf16x8 a0;
            if (l == 0) {
                unsigned int xd = xb[t * 16 + m];
                union { unsigned int u[4]; bf16x8 v; } au;
                au.u[0] = (q == 0) ? xd : 0u; au.u[1] = 0u; au.u[2] = 0u; au.u[3] = 0u;
                a0 = au.v;
            } else {
                a0 = *(const bf16x8*)(hbuf + (l - 1) * 640 + aoff); // h_{l-1}(t)
            }

            f32x4 acc[8];
            // Block R: recurrent MFMAs (weights in AGPR via "a" constraint)
            asm volatile(
                "v_mfma_f32_16x16x32_bf16 %[c0], %[A], %[w0], %[Z]\n\t"
                "v_mfma_f32_16x16x32_bf16 %[c1], %[A], %[w1], %[Z]\n\t"
                "v_mfma_f32_16x16x32_bf16 %[c2], %[A], %[w2], %[Z]\n\t"
                "v_mfma_f32_16x16x32_bf16 %[c3], %[A], %[w3], %[Z]\n\t"
                "v_mfma_f32_16x16x32_bf16 %[c4], %[A], %[w4], %[Z]\n\t"
                "v_mfma_f32_16x16x32_bf16 %[c5], %[A], %[w5], %[Z]\n\t"
                "v_mfma_f32_16x16x32_bf16 %[c6], %[A], %[w6], %[Z]\n\t"
                "v_mfma_f32_16x16x32_bf16 %[c7], %[A], %[w7], %[Z]"
                : [c0]"=&v"(acc[0]), [c1]"=&v"(acc[1]), [c2]"=&v"(acc[2]),
                  [c3]"=&v"(acc[3]), [c4]"=&v"(acc[4]), [c5]"=&v"(acc[5]),
                  [c6]"=&v"(acc[6]), [c7]"=&v"(acc[7])
                : [A]"v"(a1), [Z]"v"(zz),
                  [w0]"a"(bfr[l][0][1]), [w1]"a"(bfr[l][1][1]),
                  [w2]"a"(bfr[l][2][1]), [w3]"a"(bfr[l][3][1]),
                  [w4]"a"(bfr[l][4][1]), [w5]"a"(bfr[l][5][1]),
                  [w6]"a"(bfr[l][6][1]), [w7]"a"(bfr[l][7][1]));
            // Block I: input MFMAs, tied acc; trailing nops cover MFMA->VALU hazard
            asm volatile(
                "v_mfma_f32_16x16x32_bf16 %[c0], %[A], %[w0], %[c0]\n\t"
                "v_mfma_f32_16x16x32_bf16 %[c1], %[A], %[w1], %[c1]\n\t"
                "v_mfma_f32_16x16x32_bf16 %[c2], %[A], %[w2], %[c2]\n\t"
                "v_mfma_f32_16x16x32_bf16 %[c3], %[A], %[w3], %[c3]\n\t"
                "v_mfma_f32_16x16x32_bf16 %[c4], %[A], %[w4], %[c4]\n\t"
                "v_mfma_f32_16x16x32_bf16 %[c5], %[A], %[w5], %[c5]\n\t"
                "v_mfma_f32_16x16x32_bf16 %[c6], %[A], %[w6], %[c6]\n\t"
                "v_mfma_f32_16x16x32_bf16 %[c7], %[A], %[w7], %[c7]\n\t"
                "s_nop 7\n\t"
                "s_nop 7"
                : [c0]"+v"(acc[0]), [c1]"+v"(acc[1]), [c2]"+v"(acc[2]),
                  [c3]"+v"(acc[3]), [c4]"+v"(acc[4]), [c5]"+v"(acc[5]),
                  [c6]"+v"(acc[6]), [c7]"+v"(acc[7])
                : [A]"v"(a0),
                  [w0]"a"(bfr[l][0][0]), [w1]"a"(bfr[l][1][0]),
                  [w2]"a"(bfr[l][2][0]), [w3]"a"(bfr[l][3][0]),
                  [w4]"a"(bfr[l][4][0]), [w5]"a"(bfr[l][5][0]),
                  [w6]"a"(bfr[l][6][0]), [w7]"a"(bfr[l][7][0]));

            unsigned int* hw = (unsigned int*)(hbuf + l * 640);
            float h0[4];
#pragma unroll
            for (int hf = 0; hf < 2; ++hf) {
#pragma unroll
                for (int r = 0; r < 4; ++r) {
                    float ei = fex2(acc[0 + hf][r] + bv[l][0 + hf]);   // e^{-a_i}
                    float ef = fex2(acc[2 + hf][r] + bv[l][2 + hf]);   // e^{-a_f}
                    float eg = fex2(acc[4 + hf][r] + bv[l][4 + hf]);   // e^{-2 a_g}
                    float eo = fex2(acc[6 + hf][r] + bv[l][6 + hf]);   // e^{-a_o}
                    float ap_f = 1.0f + ef;
                    float p1   = (1.0f + ei) * (1.0f + eg);
                    float R_   = frcp(p1 * ap_f);
                    float egp  = __builtin_fmaf(eg, TWOLOG2E, NTWOLOG2E);
                    float t1   = egp * ap_f;
                    float t2   = __builtin_fmaf(cp[l][hf][r], p1, t1);
                    float cn   = t2 * R_;                     // scaled cell state
                    cp[l][hf][r] = cn;
                    float ec = fex2(cn);                      // e^{-2c}
                    float Rh = frcp((1.0f + eo) * (1.0f + ec));
                    float hh = (1.0f - ec) * Rh;
                    if (hf == 0) h0[r] = hh;
                    else hw[(q * 4 + r) * 20 + m] = pk2(h0[r], hh);
                }
            }
        }
    }

    // output head: h3(t=63) in hbuf[3]
    if (lane < 16) {
        const short* h3 = hbuf + 3 * 640 + lane * 40;
        float s = blin[0];
#pragma unroll
        for (int k = 0; k < 32; ++k)
            s += Wlin[k] * b2f((unsigned short)h3[k]);
        out[row0 + lane] = frcp(1.0f + fex2(s * NLOG2E));
    }
}

extern "C" void kernel_launch(void* const* d_in, const int* in_sizes, int n_in,
                              void* d_out, int out_size, void* d_ws, size_t ws_size,
                              hipStream_t stream) {
    const float* x    = (const float*)d_in[0];
    const float* Wih0 = (const float*)d_in[1];
    const float* Wih  = (const float*)d_in[2];
    const float* Whh  = (const float*)d_in[3];
    const float* bih  = (const float*)d_in[4];
    const float* bhh  = (const float*)d_in[5];
    const float* Wlin = (const float*)d_in[6];
    const float* blin = (const float*)d_in[7];
    float* out = (float*)d_out;

    lstm_mfma<<<1024, 64, 0, stream>>>(x, Wih0, Wih, Whh, bih, bhh, Wlin, blin, out);
}

// Round 14
// 222.106 us; speedup vs baseline: 1.1700x; 1.1700x over previous
//
#include <hip/hip_runtime.h>

typedef float  f32x4  __attribute__((ext_vector_type(4)));
typedef short  bf16x8 __attribute__((ext_vector_type(8)));

#define TWOLOG2E   2.8853900817779268f
#define NLOG2E    -1.4426950408889634f
#define NTWOLOG2E -2.8853900817779268f

__device__ __forceinline__ unsigned short f2b(float f) {      // fp32 -> bf16 RNE
    unsigned int u = __builtin_bit_cast(unsigned int, f);
    u += 0x7fffu + ((u >> 16) & 1u);
    return (unsigned short)(u >> 16);
}
__device__ __forceinline__ float b2f(unsigned short s) {
    unsigned int u = ((unsigned int)s) << 16;
    return __builtin_bit_cast(float, u);
}
__device__ __forceinline__ unsigned int pk2(float lo, float hi) {
#if __has_builtin(__builtin_amdgcn_cvt_pk_bf16_f32)
    typedef __bf16 bf16x2 __attribute__((ext_vector_type(2)));
    bf16x2 p = __builtin_amdgcn_cvt_pk_bf16_f32(lo, hi);
    return __builtin_bit_cast(unsigned int, p);
#else
    return (unsigned int)f2b(lo) | ((unsigned int)f2b(hi) << 16);
#endif
}
__device__ __forceinline__ float frcp(float x) { return __builtin_amdgcn_rcpf(x); }
__device__ __forceinline__ float fex2(float x) { return __builtin_amdgcn_exp2f(x); }

// BEST-KNOWN formulation (R9, 174 us kernel / 224 us bench, absmax 0):
// block = 256 thr = 4 waves, 32 rows (grid 512, 2 blocks/CU). Wave l owns layer
// l; its 16 B-frags (128 gate-rows x K=64 bf16) live in VGPRs, pre-scaled by
// -log2e (-2log2e for the g gate) so MFMA emits NEGATED scaled preacts; bias
// rides in the MFMA C operand (lane-uniform, splats hoisted). 2-timestep
// super-steps (35 barriers). h crosses layers via LDS [l][parity][slot][32row*40]
// bf16 A-frag layout; in-super-step recurrent read is own-wave (lgkm only).
// Epilogue per cell (minimal: 5 exp + 2 rcp, merged-rcp shared denominator):
//   p1=(1+ei)(1+eg); cn' = [cp*p1 - 2log2e(1-eg)(1+ef)] * rcp(p1*(1+ef))
//   (cp = -2log2e*c pre-scaled);  ec = exp2(cp);  h = (1-ec)*rcp((1+eo)(1+ec))
// Structural notes (measured, R7-R13): more waves/SIMD, spin-chaining, and
// fully-decoupled 1-wave/SIMD variants all regress; the ~21% residual idle is
// pipeline fill/drain + barrier convoy and resisted 4 attacks.
__global__ __launch_bounds__(256, 2)
void lstm_mfma(const float* __restrict__ xg,  const float* __restrict__ Wih0,
               const float* __restrict__ Wih, const float* __restrict__ Whh,
               const float* __restrict__ bih, const float* __restrict__ bhh,
               const float* __restrict__ Wlin,const float* __restrict__ blin,
               float* __restrict__ out) {
    __shared__ short        hb[16 * 1280] __attribute__((aligned(16))); // [l][p][slot][32row*40]
    __shared__ unsigned int xb[64 * 32];                                // [t][row] 2xbf16

    const int tid  = threadIdx.x;
    const int wv   = __builtin_amdgcn_readfirstlane(tid >> 6);  // layer id, uniform
    const int lane = tid & 63;
    const int m    = lane & 15;    // A-row / D-col index
    const int q    = lane >> 4;    // quad
    const int row0 = blockIdx.x * 32;

    // zero all h buffers (first reads must see 0)
    for (int i = tid; i < 10240; i += 256) ((unsigned int*)hb)[i] = 0u;

    // stage x -> LDS bf16 [t][row]
    for (int i = tid; i < 2048; i += 256) {
        int r = i >> 6, t = i & 63;
        float x0 = xg[(size_t)(row0 + r) * 192 + t];
        float x1 = xg[(size_t)(row0 + r) * 192 + 64 + t];
        xb[t * 32 + r] = pk2(x0, x1);
    }

    // ---- one-time gather of B-frags + bias (negated scales) ----
    // tile g: gate T=g>>1 of unit 2m+(g&1); rowG = T*32 + 2m + (g&1).
    bf16x8 bfr[8][2];
    float  bv[8];
#pragma unroll
    for (int g = 0; g < 8; ++g) {
        const int   T    = g >> 1;
        const int   rowG = T * 32 + 2 * m + (g & 1);
        const float sc   = (T == 2) ? NTWOLOG2E : NLOG2E;
        bv[g] = (bih[wv * 128 + rowG] + bhh[wv * 128 + rowG]) * sc;
#pragma unroll
        for (int c = 0; c < 2; ++c) {
            const int k0 = c * 32 + q * 8;
            float w[8];
            if (wv == 0) {
                if (c == 0) {
#pragma unroll
                    for (int jj = 0; jj < 8; ++jj) w[jj] = 0.0f;
                    if (q == 0) { w[0] = Wih0[rowG * 2]; w[1] = Wih0[rowG * 2 + 1]; }
                } else {
                    const float* src = Whh + rowG * 32 + (k0 - 32);
#pragma unroll
                    for (int jj = 0; jj < 8; ++jj) w[jj] = src[jj];
                }
            } else {
                const float* src = (c == 0) ? (Wih + (wv - 1) * 4096 + rowG * 32 + k0)
                                            : (Whh + wv * 4096 + rowG * 32 + (k0 - 32));
#pragma unroll
                for (int jj = 0; jj < 8; ++jj) w[jj] = src[jj];
            }
            bf16x8 fr;
#pragma unroll
            for (int jj = 0; jj < 8; ++jj) fr[jj] = (short)f2b(w[jj] * sc);
            bfr[g][c] = fr;
        }
    }

    float cp[2][2][4];   // scaled cell state -2log2e*c: [tt][hf][r]
#pragma unroll
    for (int tt = 0; tt < 2; ++tt)
#pragma unroll
        for (int hf = 0; hf < 2; ++hf)
#pragma unroll
            for (int r = 0; r < 4; ++r) cp[tt][hf][r] = 0.0f;

    __syncthreads();

    // one t cell-step for all 32 rows (2 row-tiles)
    auto cell_step = [&](int t, const short* pa0, const short* pa1, short* hwr) {
        bf16x8 a0[2], a1[2];
#pragma unroll
        for (int tt = 0; tt < 2; ++tt) {
            if (wv == 0) {
                unsigned int xd = xb[t * 32 + tt * 16 + m];
                union { unsigned int u[4]; bf16x8 v; } au;
                au.u[0] = (q == 0) ? xd : 0u; au.u[1] = 0u; au.u[2] = 0u; au.u[3] = 0u;
                a0[tt] = au.v;
            } else {
                a0[tt] = *(const bf16x8*)(pa0 + (tt * 16 + m) * 40 + q * 8);
            }
            a1[tt] = *(const bf16x8*)(pa1 + (tt * 16 + m) * 40 + q * 8);
        }
#pragma unroll
        for (int tt = 0; tt < 2; ++tt) {
            f32x4 acc[8];
#pragma unroll
            for (int g = 0; g < 8; ++g) {
                f32x4 cb = {bv[g], bv[g], bv[g], bv[g]};
                acc[g] = __builtin_amdgcn_mfma_f32_16x16x32_bf16(a0[tt], bfr[g][0], cb, 0, 0, 0);
                acc[g] = __builtin_amdgcn_mfma_f32_16x16x32_bf16(a1[tt], bfr[g][1], acc[g], 0, 0, 0);
            }
            float h0[4];
#pragma unroll
            for (int hf = 0; hf < 2; ++hf) {
#pragma unroll
                for (int r = 0; r < 4; ++r) {
                    float ei = fex2(acc[0 + hf][r]);          // e^{-a_i}
                    float ef = fex2(acc[2 + hf][r]);          // e^{-a_f}
                    float eg = fex2(acc[4 + hf][r]);          // e^{-2 a_g}
                    float eo = fex2(acc[6 + hf][r]);          // e^{-a_o}
                    float ap_f = 1.0f + ef;
                    float p1   = (1.0f + ei) * (1.0f + eg);
                    float R_   = frcp(p1 * ap_f);
                    float egp  = __builtin_fmaf(eg, TWOLOG2E, NTWOLOG2E); // -2log2e*(1-eg)
                    float t1   = egp * ap_f;
                    float t2   = __builtin_fmaf(cp[tt][hf][r], p1, t1);
                    float cn   = t2 * R_;                     // scaled cell state
                    cp[tt][hf][r] = cn;
                    float ec = fex2(cn);                      // e^{-2c}
                    float Rh = frcp((1.0f + eo) * (1.0f + ec));
                    float hh = (1.0f - ec) * Rh;
                    if (hf == 0) h0[r] = hh;
                    else ((unsigned int*)hwr)[(tt * 16 + q * 4 + r) * 20 + m] = pk2(h0[r], hh);
                }
            }
        }
    };

    for (int S = 0; S < 35; ++S) {
        const int t0 = 2 * (S - wv);          // wave-uniform
        if (t0 >= 0 && t0 <= 62) {
            const int p  = S & 1;
            const int pb = p ^ 1;
            short*       Lc0 = hb + ((wv * 2 + p ) * 2    ) * 1280;  // own layer, cur parity, slot0
            short*       Lc1 = Lc0 + 1280;                            // slot1
            const short* Lp1 = hb + ((wv * 2 + pb) * 2 + 1) * 1280;  // own layer, prev parity, slot1
            const int    lb  = (wv > 0) ? (wv - 1) : 0;
            const short* Dp0 = hb + ((lb * 2 + pb) * 2    ) * 1280;  // layer below, prev parity, slot0
            const short* Dp1 = Dp0 + 1280;                            // slot1

            cell_step(t0,     Dp0, Lp1, Lc0);   // t0: input h_{l-1}(t0), recurrent h_l(t0-1)
            cell_step(t0 + 1, Dp1, Lc0, Lc1);   // t1: input h_{l-1}(t1), recurrent h_l(t0)
        }
        __syncthreads();
    }

    // output head: h3(t=63) -> S=34, p=0, slot1
    if (tid < 32) {
        const short* h3 = hb + ((3 * 2 + 0) * 2 + 1) * 1280;
        float s = blin[0];
#pragma unroll
        for (int k = 0; k < 32; ++k)
            s += Wlin[k] * b2f((unsigned short)h3[tid * 40 + k]);
        out[row0 + tid] = frcp(1.0f + fex2(s * NLOG2E));
    }
}

extern "C" void kernel_launch(void* const* d_in, const int* in_sizes, int n_in,
                              void* d_out, int out_size, void* d_ws, size_t ws_size,
                              hipStream_t stream) {
    const float* x    = (const float*)d_in[0];
    const float* Wih0 = (const float*)d_in[1];
    const float* Wih  = (const float*)d_in[2];
    const float* Whh  = (const float*)d_in[3];
    const float* bih  = (const float*)d_in[4];
    const float* bhh  = (const float*)d_in[5];
    const float* Wlin = (const float*)d_in[6];
    const float* blin = (const float*)d_in[7];
    float* out = (float*)d_out;

    lstm_mfma<<<512, 256, 0, stream>>>(x, Wih0, Wih, Whh, bih, bhh, Wlin, blin, out);
}